// Round 21
// baseline (20.278 us; speedup 1.0000x reference)
//
#include <hip/hip_runtime.h>

#define SN 128
#define SPK 512

constexpr float GMIN  = 0.1f;
constexpr float PFRAC = 0.3f;
constexpr float GMAX  = 1.0f;

typedef float  nfloat4 __attribute__((ext_vector_type(4)));   // native vec4

// LDS-composed half-plane tiles (64x64 per block), max write overlap.
// Lazy decay: v(n) = C(n)*a + GMIN, C(n) = exp((ts0-ts[n])/TAU) <= 1.
// Untouched cell at snapshot r: u_r = GMIN*(1-C_r) (identical everywhere).
// Touch at n: a' = (1-PFRAC)*a + PFRAC*(GMAX-GMIN)/C(n); amplitude is
// non-decreasing over the touch prefix -> per-touch own-prefix candidates +
// max reproduce the exact final value (verified absmax 0.0, R11/R17/R18/R19).
// Same-cell predecessors: hash-count buckets; only events in buckets with
// count>=2 are compacted (time order) and scanned (no false negatives).
//
// Block = (s, r, p): one 64x64 polarity plane built in LDS (16 KB tile,
// aliased by the 4096-bucket hash during prep), then one nontemporal
// coalesced 16 KB writeout. 2048 blocks x 256 threads (~7 blocks/CU) so
// write bursts overlap chip-wide. Prep = 2 rounds of 256 events.

__global__ __launch_bounds__(256, 4) void fuse_kernel(
    const int*   __restrict__ event,   // (SN, SPK, 3) int32: x, y, pol
    const float* __restrict__ ts,      // (SN, SPK) f32, ascending
    const int*   __restrict__ tt,      // (SN, SPK) int32 in [0,8)
    const int*   __restrict__ length,  // (SN,) int32
    float*       __restrict__ out)     // (SN, 8, 2, 64, 64) f32
{
    __shared__ int      tile[4096];    // 16 KB; aliased as hcnt during prep
    __shared__ float    stsn[SPK];
    __shared__ unsigned lpk [SPK];     // ambiguous list: (n<<16)|key, time order
    __shared__ float    lCr [SPK];
    __shared__ int      snl [8];
    __shared__ int      wcnt[8];       // 2 rounds x 4 waves
    __shared__ float    sCx;
    __shared__ int      sNrx;

    unsigned* hcnt = (unsigned*)tile;  // 4096 buckets (dead after P2)

    const int blk  = blockIdx.x;
    const int s    = blk >> 4;
    const int r    = (blk >> 1) & 7;
    const int p    = blk & 1;
    const int t    = threadIdx.x;      // 0..255
    const int lane = t & 63;
    const int wid  = t >> 6;           // 0..3

    const int   len = length[s];
    const float ts0 = ts[s * SPK];

    // ---- P0: init hash/snl + load 2 events (n0 = t, n1 = t+256) ----
#pragma unroll
    for (int k = 0; k < 16; ++k) hcnt[t + k * 256] = 0u;
    if (t < 8) snl[t] = -1;

    int ex[2], ey[2], ep[2], tv[2]; float tsn[2], myCr[2];
    bool gate[2]; unsigned key[2], h[2];
#pragma unroll
    for (int q = 0; q < 2; ++q) {
        int n = t + q * 256;
        const int* ev = event + (size_t)(s * SPK + n) * 3;
        ex[q] = ev[0]; ey[q] = ev[1]; ep[q] = ev[2];
        tsn[q]  = ts[s * SPK + n];
        tv[q]   = tt[s * SPK + n];
        gate[q] = (n < len);                             // n==0 always (len>=1)
        key[q]  = (unsigned)((ep[q] << 14) | (ex[q] << 7) | ey[q]);
        h[q]    = (key[q] * 2654435761u) >> 20;          // 12-bit bucket
        myCr[q] = (PFRAC * (GMAX - GMIN)) * __expf(-(ts0 - tsn[q]) * 0.01f);
    }
    __syncthreads();

    // ---- P1: stage (LDS atomics) ----
#pragma unroll
    for (int q = 0; q < 2; ++q) {
        int n = t + q * 256;
        stsn[n] = tsn[q];
        if (n >= 1)  atomicMax(&snl[tv[q]], n);
        if (gate[q]) atomicAdd(&hcnt[h[q]], 1u);
    }
    __syncthreads();

    // ---- P2: ambiguity flags + slot table (all hcnt reads here) ----
    bool amb[2];
    unsigned long long bm[2];
#pragma unroll
    for (int q = 0; q < 2; ++q) {
        amb[q] = gate[q] && (hcnt[h[q]] > 1u);
        bm[q]  = __ballot(amb[q]);
        if (lane == 0) wcnt[q * 4 + wid] = (int)__popcll(bm[q]);
    }
    if (t == 0) {
        int nr = snl[r];
        if (r == 0 && nr < 0) nr = 0;                    // slot0 -> init state
        float C = 0.0f;
        if (nr >= 0) C = __expf((ts0 - stsn[nr]) * 0.01f);   // C_r <= 1
        sNrx = nr; sCx = C;
    }
    __syncthreads();                                     // hcnt dead from here

    // ---- P3: compact ambiguous (time order) + tile memset to u_r ----
    int base0 = 0, base1 = 0, nA = 0;
#pragma unroll
    for (int w = 0; w < 8; ++w) {
        int c = wcnt[w];
        if (w < wid)     base0 += c;
        if (w < 4 + wid) base1 += c;
        nA += c;
    }
    const unsigned long long lmask = (1ull << lane) - 1ull;
    if (amb[0]) {
        int pos = base0 + (int)__popcll(bm[0] & lmask);
        lpk[pos] = ((unsigned)t << 16) | key[0];
        lCr[pos] = myCr[0];
    }
    if (amb[1]) {
        int pos = base1 + (int)__popcll(bm[1] & lmask);
        lpk[pos] = ((unsigned)(t + 256) << 16) | key[1];
        lCr[pos] = myCr[1];
    }
    const int   nr  = sNrx;
    const float C_r = sCx;
    const int   ub  = __float_as_int((nr >= 0) ? (GMIN - C_r * GMIN) : 0.0f);
    {
        int4 u4; u4.x = u4.y = u4.z = u4.w = ub;
        int4* T = (int4*)tile;
#pragma unroll
        for (int k = 0; k < 4; ++k) T[t + k * 256] = u4;
    }
    __syncthreads();                                     // tile + lpk/lCr ready

    // ---- P4: own-prefix amplitude + LDS scatter ----
#pragma unroll
    for (int q = 0; q < 2; ++q) {
        int n = t + q * 256;
        if (gate[q] && ep[q] == p && n <= nr) {
            float a = -GMIN;
            if (amb[q]) {
                for (int i = 0; i < nA; ++i) {
                    unsigned e = lpk[i];
                    if ((e & 0xFFFFu) == key[q] && (e >> 16) < (unsigned)n)
                        a = ((e >> 16) == 0u)
                                ? (PFRAC * (GMAX - GMIN) - GMIN)  // init SETs .27
                                : fmaf(1.0f - PFRAC, a, lCr[i]);
                }
            }
            a = (n == 0) ? (PFRAC * (GMAX - GMIN) - GMIN)
                         : fmaf(1.0f - PFRAC, a, myCr[q]);
            float val = fmaf(C_r, a, GMIN);              // >= u_r >= 0
            int   idx = ((ex[q] >> 1) * 64) + (ey[q] >> 1);
            atomicMax(&tile[idx], __float_as_int(val));
        }
    }
    __syncthreads();

    // ---- P5: nontemporal coalesced writeout (1024 x 16B) ----
    nfloat4*       o4 = (nfloat4*)(out + (size_t)(((s * 8 + r) * 2 + p)) * 4096);
    const nfloat4* t4 = (const nfloat4*)tile;
#pragma unroll
    for (int k = 0; k < 4; ++k)
        __builtin_nontemporal_store(t4[t + k * 256], o4 + t + k * 256);
}

extern "C" void kernel_launch(void* const* d_in, const int* in_sizes, int n_in,
                              void* d_out, int out_size, void* d_ws, size_t ws_size,
                              hipStream_t stream) {
    const int*   event  = (const int*)  d_in[0];
    const float* ts     = (const float*)d_in[1];
    const int*   tt     = (const int*)  d_in[2];
    const int*   length = (const int*)  d_in[3];
    float*       out    = (float*)d_out;

    // 128 samples x 8 slots x 2 polarities = 2048 blocks x 256 threads
    fuse_kernel<<<dim3(SN * 8 * 2), dim3(256), 0, stream>>>(event, ts, tt, length, out);
}

// Round 22
// 16.768 us; speedup vs baseline: 1.2093x; 1.2093x over previous
//
#include <hip/hip_runtime.h>

#define SN 128
#define SPK 512

constexpr float GMIN  = 0.1f;
constexpr float PFRAC = 0.3f;
constexpr float GMAX  = 1.0f;

// LDS-composed output tile, single global writeout (R18 base) with cheap
// per-slot snlast: the block only needs snl[r] for ITS slot r, so one ballot
// per wave + 8-entry reduce replaces 512 same-address LDS atomicMax.
//
// Lazy decay: v(n) = C(n)*a + GMIN, C(n) = exp((ts0-ts[n])/TAU) <= 1.
// Untouched cell at snapshot r: u_r = GMIN*(1-C_r) (identical everywhere).
// Touch at n: a' = (1-PFRAC)*a + PFRAC*(GMAX-GMIN)/C(n); amplitude is
// non-decreasing over the touch prefix -> per-touch own-prefix candidates +
// max reproduce the exact final value (verified absmax 0.0, R11/R17-R21).
// Same-cell predecessors: hash-count buckets; only events in buckets with
// count>=2 are compacted (time order) and scanned (no false negatives).
//
// Block = (s, r): one output plane (2 pol x 64 x 64 = 32 KB) built in LDS:
// memset to u_r -> LDS atomicMax scatter -> coalesced 32 KB writeout.

__global__ __launch_bounds__(512, 4) void fuse_kernel(
    const int*   __restrict__ event,   // (SN, SPK, 3) int32: x, y, pol
    const float* __restrict__ ts,      // (SN, SPK) f32, ascending
    const int*   __restrict__ tt,      // (SN, SPK) int32 in [0,8)
    const int*   __restrict__ length,  // (SN,) int32
    float*       __restrict__ out)     // (SN, 8, 2, 64, 64) f32
{
    __shared__ int      tile[2 * 64 * 64];   // 32 KB; first 16 KB aliased as hcnt
    __shared__ float    stsn[SPK];
    __shared__ unsigned lpk [SPK];           // ambiguous list: (n<<16)|key
    __shared__ float    lCr [SPK];
    __shared__ int      wlast[8];            // per-wave last occurrence of slot r
    __shared__ int      wcnt [8];
    __shared__ float    sCs;                 // C_r
    __shared__ int      sNr;                 // n_r
    __shared__ int      sUb;                 // bits(u_r)

    unsigned* hcnt = (unsigned*)tile;        // 4096 buckets (dead after P2)

    const int blk  = blockIdx.x;
    const int s    = blk >> 3;
    const int r    = blk & 7;
    const int t    = threadIdx.x;            // event index n = t
    const int lane = t & 63;
    const int wid  = t >> 6;                 // 0..7

    const int   len = length[s];
    const float ts0 = ts[s * SPK];

    // issue event loads early
    const int* ev = event + (size_t)(s * SPK + t) * 3;
    const int   ex  = ev[0], ey = ev[1], ep = ev[2];
    const float tsn = ts[s * SPK + t];
    const int   tv  = tt[s * SPK + t];

    // ---- P0: init hash buckets ----
#pragma unroll
    for (int k = 0; k < 8; ++k) hcnt[t + k * 512] = 0u;
    __syncthreads();

    // ---- P1: stage + hash count + per-wave snlast ballot ----
    const bool     gate = (t < len);                    // t==0 always (len>=1)
    const unsigned key  = (unsigned)((ep << 14) | (ex << 7) | ey);
    const float    myCr = (PFRAC * (GMAX - GMIN)) * __expf(-(ts0 - tsn) * 0.01f);
    const unsigned h    = (key * 2654435761u) >> 20;    // 12-bit bucket
    stsn[t] = tsn;
    if (gate) atomicAdd(&hcnt[h], 1u);
    {
        unsigned long long m = __ballot(t >= 1 && tv == r);
        if (lane == 0)
            wlast[wid] = m ? (wid * 64 + 63 - (int)__clzll(m)) : -1;
    }
    __syncthreads();

    // ---- P2: slot table (thread 0) + ambiguity flags (all hcnt reads) ----
    if (t == 0) {
        int nr = wlast[0];
#pragma unroll
        for (int w = 1; w < 8; ++w) nr = max(nr, wlast[w]);
        if (r == 0 && nr < 0) nr = 0;                   // slot0 -> init state
        float C = 0.0f;
        if (nr >= 0) C = __expf((ts0 - stsn[nr]) * 0.01f);   // C_r <= 1
        sNr = nr;
        sCs = C;
        sUb = __float_as_int((nr >= 0) ? (GMIN - C * GMIN) : 0.0f);
    }
    const bool amb = gate && (hcnt[h] > 1u);
    const unsigned long long bm = __ballot(amb);
    if (lane == 0) wcnt[wid] = (int)__popcll(bm);
    __syncthreads();                                    // hcnt dead from here

    // ---- P3: compact ambiguous (time order) + tile memset to u_r ----
    int base = 0, nA = 0;
#pragma unroll
    for (int w = 0; w < 8; ++w) {
        int c = wcnt[w];
        if (w < wid) base += c;
        nA += c;
    }
    if (amb) {
        int pos = base + (int)__popcll(bm & ((1ull << lane) - 1ull));
        lpk[pos] = ((unsigned)t << 16) | key;
        lCr[pos] = myCr;
    }
    const int   nr  = sNr;
    const float C_r = sCs;
    {
        int4 u4; u4.x = u4.y = u4.z = u4.w = sUb;
        int4* T = (int4*)tile;
#pragma unroll
        for (int k = 0; k < 4; ++k) T[t + k * 512] = u4;
    }
    __syncthreads();                                    // tile + lpk/lCr ready

    // ---- P4: own-prefix amplitude + LDS scatter ----
    if (gate && t <= nr) {
        float a = -GMIN;
        if (amb) {
            for (int i = 0; i < nA; ++i) {
                unsigned e = lpk[i];
                if ((e & 0xFFFFu) == key && (e >> 16) < (unsigned)t)
                    a = ((e >> 16) == 0u)
                            ? (PFRAC * (GMAX - GMIN) - GMIN)   // init SETs 0.27
                            : fmaf(1.0f - PFRAC, a, lCr[i]);
            }
        }
        a = (t == 0) ? (PFRAC * (GMAX - GMIN) - GMIN)
                     : fmaf(1.0f - PFRAC, a, myCr);
        float val = fmaf(C_r, a, GMIN);                 // >= u_r >= 0
        int   idx = (ep * 64 + (ex >> 1)) * 64 + (ey >> 1);
        atomicMax(&tile[idx], __float_as_int(val));
    }
    __syncthreads();

    // ---- P5: single coalesced writeout (2048 float4) ----
    float4*       o4 = reinterpret_cast<float4*>(out + (size_t)(s * 8 + r) * 8192);
    const float4* t4 = reinterpret_cast<const float4*>(tile);
#pragma unroll
    for (int k = 0; k < 4; ++k) o4[t + k * 512] = t4[t + k * 512];
}

extern "C" void kernel_launch(void* const* d_in, const int* in_sizes, int n_in,
                              void* d_out, int out_size, void* d_ws, size_t ws_size,
                              hipStream_t stream) {
    const int*   event  = (const int*)  d_in[0];
    const float* ts     = (const float*)d_in[1];
    const int*   tt     = (const int*)  d_in[2];
    const int*   length = (const int*)  d_in[3];
    float*       out    = (float*)d_out;

    // 128 samples x 8 slots = 1024 blocks x 512 threads
    fuse_kernel<<<dim3(SN * 8), dim3(512), 0, stream>>>(event, ts, tt, length, out);
}